// Round 12
// baseline (34.999 us; speedup 1.0000x reference)
//
#include <hip/hip_runtime.h>

// QuantumAttention: out[b,s,e] = sum_q q[b,s,q] * W_dec[e,q] + x[b,s,e]
//   angles = x @ W_enc^T, c = cos(angles)
//   q[0] = prod(c[1..7]); q[i] = prod(c[0..i])
//
// R12: 2-wave blocks, 8 e/lane, sync radius minimized.
//  - wave all-reduce is pure VALU and ALL-LANE-VALID: 4x DPP row_ror adds
//    (row sums in every lane) + permlane16_swap + permlane32_swap pair-sums.
//    -> no wave0 serial phase, no LDS broadcast fan-out, ONE barrier/token.
//  - cross-wave combine: lane0 writes 8 floats, raw s_barrier (lgkm only),
//    2 broadcast ds_read_b128. 8 LDS instrs/token (4-wave designs: ~40).
//  - weights register-resident: wenc q-pair packed (64 f32) + wdec rows
//    (64 f32); x = 8 floats + depth-1 prefetch.
//  - plain stores (NT dropped as A/B).

typedef float v2f __attribute__((ext_vector_type(2)));
typedef float v4f __attribute__((ext_vector_type(4)));
typedef unsigned int v2u __attribute__((ext_vector_type(2)));

#define EDIM 1024
#define QDIM 8
#define NTOK 16384
#define BLOCK 128
#define TPB 8
#define GRID (NTOK / TPB)   // 2048 blocks x 2 waves

// v += dpp_move(v); row_ror wraps within 16-lane rows (no OOB lanes)
template<int CTRL>
__device__ __forceinline__ float dpp_add(float v) {
    int m = __builtin_amdgcn_update_dpp(0, __float_as_int(v), CTRL, 0xF, 0xF, true);
    return v + __int_as_float(m);
}

// 64-lane sum, result valid in ALL lanes, zero DS ops.
__device__ __forceinline__ float wave_allsum(float v) {
    v = dpp_add<0x121>(v);   // row_ror:1
    v = dpp_add<0x122>(v);   // row_ror:2
    v = dpp_add<0x124>(v);   // row_ror:4
    v = dpp_add<0x128>(v);   // row_ror:8  -> every lane holds its row-of-16 sum
#if __has_builtin(__builtin_amdgcn_permlane16_swap)
    {   // r.x = a[lane & ~16], r.y = a[lane | 16]  ->  sum = a + a[lane^16]
        unsigned u = __float_as_uint(v);
        v2u r = __builtin_amdgcn_permlane16_swap(u, u, false, false);
        v = __uint_as_float(r.x) + __uint_as_float(r.y);
    }
#else
    v += __shfl_xor(v, 16, 64);
#endif
#if __has_builtin(__builtin_amdgcn_permlane32_swap)
    {   // r.x = a[lane & ~32], r.y = a[lane | 32]  ->  sum = a + a[lane^32]
        unsigned u = __float_as_uint(v);
        v2u r = __builtin_amdgcn_permlane32_swap(u, u, false, false);
        v = __uint_as_float(r.x) + __uint_as_float(r.y);
    }
#else
    v += __shfl_xor(v, 32, 64);
#endif
    return v;
}

__global__ __launch_bounds__(BLOCK, 2)
void qattn_kernel(const float* __restrict__ x,
                  const float* __restrict__ W_enc,   // [Q][E]
                  const float* __restrict__ W_dec,   // [E][Q]
                  float* __restrict__ out)
{
    __shared__ float part[2][2][QDIM];   // [parity][wave][q] = 128 B

    const int t    = threadIdx.x;
    const int lane = t & 63;
    const int wave = t >> 6;
    const int eb   = wave * 512 + lane * 4;   // own elems: eb + j*256 + k
    const int tok0 = blockIdx.x * TPB;

    // ---- encode weights, q-pair packed: wencp[p][j*4+k] = {W[2p][e], W[2p+1][e]} ----
    v2f wencp[4][8];
#pragma unroll
    for (int p = 0; p < 4; ++p) {
#pragma unroll
        for (int j = 0; j < 2; ++j) {
            v4f wa = *(const v4f*)(W_enc + (2 * p)     * EDIM + eb + j * 256);
            v4f wb = *(const v4f*)(W_enc + (2 * p + 1) * EDIM + eb + j * 256);
#pragma unroll
            for (int k = 0; k < 4; ++k)
                wencp[p][j * 4 + k] = (v2f){wa[k], wb[k]};
        }
    }
    // ---- decode weights: per own elem, its 8-q row as two v4f ----
    v4f wdlo[8], wdhi[8];
#pragma unroll
    for (int j = 0; j < 2; ++j)
#pragma unroll
        for (int k = 0; k < 4; ++k) {
            const int e = eb + j * 256 + k;
            wdlo[j * 4 + k] = *(const v4f*)(W_dec + e * QDIM);
            wdhi[j * 4 + k] = *(const v4f*)(W_dec + e * QDIM + 4);
        }

    // ---- first token's x ----
    v4f xv0 = *(const v4f*)(x + (size_t)tok0 * EDIM + eb);
    v4f xv1 = *(const v4f*)(x + (size_t)tok0 * EDIM + eb + 256);

    for (int it = 0; it < TPB; ++it) {
        const int tok = tok0 + it;

        // depth-1 prefetch of next token's x
        v4f xn0 = (v4f){0.f, 0.f, 0.f, 0.f}, xn1 = xn0;
        if (it + 1 < TPB) {
            xn0 = *(const v4f*)(x + (size_t)(tok + 1) * EDIM + eb);
            xn1 = *(const v4f*)(x + (size_t)(tok + 1) * EDIM + eb + 256);
        }

        // ---- encode: q-pair packed pk_fma over own 8 elems ----
        v2f acc[4];
#pragma unroll
        for (int p = 0; p < 4; ++p) acc[p] = (v2f){0.f, 0.f};
#pragma unroll
        for (int j = 0; j < 2; ++j)
#pragma unroll
            for (int k = 0; k < 4; ++k) {
                const float xe = (j == 0) ? xv0[k] : xv1[k];
                const v2f xee = (v2f){xe, xe};
#pragma unroll
                for (int p = 0; p < 4; ++p)
                    acc[p] = __builtin_elementwise_fma(xee, wencp[p][j * 4 + k], acc[p]);
            }

        // ---- all-lane wave reduce (pure VALU) ----
        float own[QDIM];
#pragma unroll
        for (int p = 0; p < 4; ++p) {
            own[2 * p]     = wave_allsum(acc[p].x);
            own[2 * p + 1] = wave_allsum(acc[p].y);
        }

        // ---- cross-wave: lane0 publishes, ONE raw barrier, 2 broadcast reads ----
        const int par = it & 1;
        if (lane == 0) {
            *(v4f*)&part[par][wave][0] = (v4f){own[0], own[1], own[2], own[3]};
            *(v4f*)&part[par][wave][4] = (v4f){own[4], own[5], own[6], own[7]};
        }
        asm volatile("s_waitcnt lgkmcnt(0)" ::: "memory");
        __builtin_amdgcn_s_barrier();
        asm volatile("" ::: "memory");

        v4f olo = *(const v4f*)&part[par][wave ^ 1][0];
        v4f ohi = *(const v4f*)&part[par][wave ^ 1][4];

        float c[QDIM];
        c[0] = __cosf(own[0] + olo[0]); c[1] = __cosf(own[1] + olo[1]);
        c[2] = __cosf(own[2] + olo[2]); c[3] = __cosf(own[3] + olo[3]);
        c[4] = __cosf(own[4] + ohi[0]); c[5] = __cosf(own[5] + ohi[1]);
        c[6] = __cosf(own[6] + ohi[2]); c[7] = __cosf(own[7] + ohi[3]);

        // ---- q-values (lane-redundant, 13 muls) ----
        float qv[QDIM];
        float q0 = c[1];
#pragma unroll
        for (int q = 2; q < QDIM; ++q) q0 *= c[q];
        qv[0] = q0;
        float pr = c[0];
#pragma unroll
        for (int q = 1; q < QDIM; ++q) { pr *= c[q]; qv[q] = pr; }

        const v2f qp0 = (v2f){qv[0], qv[1]};
        const v2f qp1 = (v2f){qv[2], qv[3]};
        const v2f qp2 = (v2f){qv[4], qv[5]};
        const v2f qp3 = (v2f){qv[6], qv[7]};

        // ---- decode own 8 elems (residual seeded into fma chain) + store ----
#pragma unroll
        for (int j = 0; j < 2; ++j) {
            float od[4];
#pragma unroll
            for (int k = 0; k < 4; ++k) {
                const int e = j * 4 + k;
                const float xe = (j == 0) ? xv0[k] : xv1[k];
                v2f a = __builtin_elementwise_fma(
                            qp0, (v2f){wdlo[e].x, wdlo[e].y}, (v2f){xe, 0.f});
                a = __builtin_elementwise_fma(qp1, (v2f){wdlo[e].z, wdlo[e].w}, a);
                a = __builtin_elementwise_fma(qp2, (v2f){wdhi[e].x, wdhi[e].y}, a);
                a = __builtin_elementwise_fma(qp3, (v2f){wdhi[e].z, wdhi[e].w}, a);
                od[k] = a.x + a.y;
            }
            *(v4f*)(out + (size_t)tok * EDIM + eb + j * 256) =
                (v4f){od[0], od[1], od[2], od[3]};
        }

        xv0 = xn0; xv1 = xn1;
    }
}

extern "C" void kernel_launch(void* const* d_in, const int* in_sizes, int n_in,
                              void* d_out, int out_size, void* d_ws, size_t ws_size,
                              hipStream_t stream) {
    const float* x     = (const float*)d_in[0];
    const float* W_enc = (const float*)d_in[1];
    const float* W_dec = (const float*)d_in[2];
    float* out         = (float*)d_out;
    (void)d_ws; (void)ws_size;

    hipLaunchKernelGGL(qattn_kernel, dim3(GRID), dim3(BLOCK), 0, stream,
                       x, W_enc, W_dec, out);
}